// Round 1
// baseline (1350.865 us; speedup 1.0000x reference)
//
#include <hip/hip_runtime.h>

#define N_NODES 50000
#define N_EDGES 800000
#define TT 2048  // LUT intervals over d in [0,5]

__device__ __forceinline__ float silu_f(float z) {
  return __fdividef(z, 1.0f + __expf(-z));
}

__device__ __forceinline__ float rlane(float v, int lane) {
  return __builtin_bit_cast(float, __builtin_amdgcn_readlane(__builtin_bit_cast(int, v), lane));
}

// ---------------- repack w_int (132x132) into wm (132x128) + wb (132x4) ----------------
__global__ void repack_w_kernel(const float* __restrict__ w_int,
                                float* __restrict__ wm, float* __restrict__ wb) {
  int idx = blockIdx.x * 256 + threadIdx.x;
  if (idx < 132 * 132) {
    int k = idx / 132;
    int j = idx - k * 132;
    float v = w_int[idx];
    if (j < 128) wm[k * 128 + j] = v;
    else         wb[k * 4 + (j - 128)] = v;
  }
}

// ---------------- LUT build: h(d) for fi and fe, 2049 entries x 256 cols ----------------
struct LutW {
  const float *w1a, *b1a, *w2a, *b2a;
  const float *w1b, *b1b, *w2b, *b2b;
};

__global__ __launch_bounds__(128) void lut_build_kernel(LutW W, float* __restrict__ lut) {
  __shared__ float rbf[8][32];
  __shared__ float h1[8][128];
  const int tid = threadIdx.x;          // 0..127 (output column)
  const int j0 = blockIdx.x * 8;
  // gaussian rbf for 8 grid points
  for (int idx = tid; idx < 8 * 32; idx += 128) {
    int jj = idx >> 5, k = idx & 31;
    float d = (float)(j0 + jj) * (5.0f / (float)TT);
    float x = d - (float)k * (5.0f / 31.0f);
    rbf[jj][k] = __expf(-19.22f * x * x);   // gamma = 0.5/(5/31)^2 = 19.22
  }
  __syncthreads();
  for (int f = 0; f < 2; ++f) {
    const float* w1 = f ? W.w1b : W.w1a;
    const float* b1 = f ? W.b1b : W.b1a;
    const float* w2 = f ? W.w2b : W.w2a;
    const float* b2 = f ? W.b2b : W.b2a;
    float acc[8];
    float bb = b1[tid];
#pragma unroll
    for (int jj = 0; jj < 8; jj++) acc[jj] = bb;
    for (int k = 0; k < 32; k++) {
      float w = w1[k * 128 + tid];
#pragma unroll
      for (int jj = 0; jj < 8; jj++) acc[jj] = fmaf(rbf[jj][k], w, acc[jj]);
    }
#pragma unroll
    for (int jj = 0; jj < 8; jj++) h1[jj][tid] = silu_f(acc[jj]);
    __syncthreads();
    float acc2[8];
    float bb2 = b2[tid];
#pragma unroll
    for (int jj = 0; jj < 8; jj++) acc2[jj] = bb2;
    for (int k = 0; k < 128; k++) {
      float w = w2[k * 128 + tid];
#pragma unroll
      for (int jj = 0; jj < 8; jj++) acc2[jj] = fmaf(h1[jj][k], w, acc2[jj]);
    }
#pragma unroll
    for (int jj = 0; jj < 8; jj++) {
      int j = j0 + jj;
      if (j <= TT) lut[(size_t)j * 256 + f * 128 + tid] = silu_f(acc2[jj]);
    }
    __syncthreads();   // h1 reused by next filter
  }
}

// ---------------- node kernel: t = x @ w_int + b, out0/out1 epilogues ----------------
__global__ __launch_bounds__(256) void node_kernel(
    const float* __restrict__ inv_f, const float* __restrict__ ev_f,
    const float* __restrict__ wm, const float* __restrict__ wb,
    const float* __restrict__ b_int,
    float* __restrict__ out0, float* __restrict__ out1) {
  __shared__ __align__(16) float xt[132][40];  // x transposed: [k][node], pad 40 (16B-aligned rows, 4-way wr conflict only)
  __shared__ float aev[32][17];
  __shared__ float tb[32][5];
  __shared__ float bint[132];
  const int tid = threadIdx.x;
  if (tid < 132) bint[tid] = b_int[tid];
  const int cg = tid & 31;   // col group: cols 4cg..4cg+3
  const int ng = tid >> 5;   // node group: nodes 4ng..4ng+3
  for (int n0 = blockIdx.x * 32; n0 < N_NODES; n0 += gridDim.x * 32) {
    __syncthreads();   // protect xt/aev/tb from previous iteration readers
    // stage x: att_inv part (vectorized), coalesced global reads
    for (int idx = tid; idx < 32 * 32; idx += 256) {
      int nn = idx >> 5, k4 = idx & 31;
      int n = n0 + nn;
      if (n < N_NODES) {
        float4 v = *(const float4*)(inv_f + (size_t)n * 128 + 4 * k4);
        xt[4 * k4 + 0][nn] = 2.0f * v.x;
        xt[4 * k4 + 1][nn] = 2.0f * v.y;
        xt[4 * k4 + 2][nn] = 2.0f * v.z;
        xt[4 * k4 + 3][nn] = 2.0f * v.w;
      }
    }
    // stage ev: att_ev and segment invariants
    if (tid < 32) {
      int n = n0 + tid;
      if (n < N_NODES) {
        float s0 = 0.f, s1 = 0.f, s2 = 0.f, s3 = 0.f;
#pragma unroll
        for (int q = 0; q < 4; q++) {
          float4 v = *(const float4*)(ev_f + (size_t)n * 16 + 4 * q);
          float e0 = 2.f * v.x, e1 = 2.f * v.y, e2 = 2.f * v.z, e3 = 2.f * v.w;
          aev[tid][4 * q + 0] = e0; aev[tid][4 * q + 1] = e1;
          aev[tid][4 * q + 2] = e2; aev[tid][4 * q + 3] = e3;
          int i0 = 4 * q;
          float qq[4] = {e0 * e0, e1 * e1, e2 * e2, e3 * e3};
#pragma unroll
          for (int c = 0; c < 4; c++) {
            int i = i0 + c;
            if (i == 0) s0 += qq[c];
            else if (i < 4) s1 += qq[c];
            else if (i < 9) s2 += qq[c];
            else s3 += qq[c];
          }
        }
        xt[128][tid] = s0; xt[129][tid] = s1; xt[130][tid] = s2; xt[131][tid] = s3;
      }
    }
    __syncthreads();
    // main GEMM: 4 nodes x 4 cols per thread; W streamed from L2
    float acc[4][4];
#pragma unroll
    for (int i = 0; i < 4; i++)
#pragma unroll
      for (int c = 0; c < 4; c++) acc[i][c] = bint[4 * cg + c];
    for (int k = 0; k < 132; k++) {
      float4 w = *(const float4*)(wm + (size_t)k * 128 + 4 * cg);
      float4 xv = *(const float4*)(&xt[k][4 * ng]);
      acc[0][0] = fmaf(xv.x, w.x, acc[0][0]); acc[0][1] = fmaf(xv.x, w.y, acc[0][1]);
      acc[0][2] = fmaf(xv.x, w.z, acc[0][2]); acc[0][3] = fmaf(xv.x, w.w, acc[0][3]);
      acc[1][0] = fmaf(xv.y, w.x, acc[1][0]); acc[1][1] = fmaf(xv.y, w.y, acc[1][1]);
      acc[1][2] = fmaf(xv.y, w.z, acc[1][2]); acc[1][3] = fmaf(xv.y, w.w, acc[1][3]);
      acc[2][0] = fmaf(xv.z, w.x, acc[2][0]); acc[2][1] = fmaf(xv.z, w.y, acc[2][1]);
      acc[2][2] = fmaf(xv.z, w.z, acc[2][2]); acc[2][3] = fmaf(xv.z, w.w, acc[2][3]);
      acc[3][0] = fmaf(xv.w, w.x, acc[3][0]); acc[3][1] = fmaf(xv.w, w.y, acc[3][1]);
      acc[3][2] = fmaf(xv.w, w.z, acc[3][2]); acc[3][3] = fmaf(xv.w, w.w, acc[3][3]);
    }
    // b_ev columns (128..131): 128 threads, one (node, col) each
    if (tid < 128) {
      int nn2 = tid >> 2, jb = tid & 3;
      float a = bint[128 + jb];
      for (int k = 0; k < 132; k++) a = fmaf(xt[k][nn2], wb[k * 4 + jb], a);
      tb[nn2][jb] = a;
    }
    __syncthreads();
    // epilogue out0 = att_inv + t[:, :128]
#pragma unroll
    for (int i = 0; i < 4; i++) {
      int n = n0 + 4 * ng + i;
      if (n < N_NODES) {
        float4 o;
        o.x = acc[i][0] + xt[4 * cg + 0][4 * ng + i];
        o.y = acc[i][1] + xt[4 * cg + 1][4 * ng + i];
        o.z = acc[i][2] + xt[4 * cg + 2][4 * ng + i];
        o.w = acc[i][3] + xt[4 * cg + 3][4 * ng + i];
        *(float4*)(out0 + (size_t)n * 128 + 4 * cg) = o;
      }
    }
    // epilogue out1 = att_ev * (1 + t[:, 128+seg])
    for (int idx = tid; idx < 512; idx += 256) {
      int nn3 = idx >> 4, i = idx & 15;
      int n = n0 + nn3;
      if (n < N_NODES) {
        int sg = (i == 0) ? 0 : (i < 4) ? 1 : (i < 9) ? 2 : 3;
        out1[(size_t)n * 16 + i] = aev[nn3][i] * (1.0f + tb[nn3][sg]);
      }
    }
  }
}

// ---------------- edge kernel: one wave per edge ----------------
struct EdgeW {
  const float *we1_fi, *be1_fi, *we2_fi, *be2_fi;
  const float *we1_fe, *be1_fe, *we2_fe, *be2_fe;
};

__global__ __launch_bounds__(256) void edge_kernel(
    const float* __restrict__ ev_f,
    const int* __restrict__ senders, const int* __restrict__ receivers,
    const float* __restrict__ lengths,
    const float* __restrict__ lut,
    EdgeW W,
    float* __restrict__ out2, float* __restrict__ out3) {
  const int L = threadIdx.x & 63;
  const int wave = blockIdx.x * (blockDim.x >> 6) + (threadIdx.x >> 6);
  const int nw = gridDim.x * (blockDim.x >> 6);

  // preload e1 weights: lane's column of we1 (lanes 0-31: fi, 32-63: fe)
  const int c1 = L & 31;
  const float* w1p = (L < 32) ? W.we1_fi : W.we1_fe;
  const float* b1p = (L < 32) ? W.be1_fi : W.be1_fe;
  const float w10 = w1p[c1], w11 = w1p[32 + c1], w12 = w1p[64 + c1], w13 = w1p[96 + c1];
  const float b1 = b1p[c1];
  // preload e2 weights for cols {2L, 2L+1}, both filters -> 128 VGPRs
  float2 wfi[32], wfe[32];
#pragma unroll
  for (int k = 0; k < 32; k++) {
    wfi[k] = *(const float2*)(W.we2_fi + k * 128 + 2 * L);
    wfe[k] = *(const float2*)(W.we2_fe + k * 128 + 2 * L);
  }
  const float2 b2fi = *(const float2*)(W.be2_fi + 2 * L);
  const float2 b2fe = *(const float2*)(W.be2_fe + 2 * L);

  for (int e = wave; e < N_EDGES; e += nw) {
    const int s = senders[e];
    const int r = receivers[e];
    const float d = lengths[e];
    // LUT lerp setup; issue LUT loads early
    float tpos = d * ((float)TT / 5.0f);
    int idx = (int)tpos;
    idx = idx < 0 ? 0 : (idx > TT - 1 ? TT - 1 : idx);
    const float fr = tpos - (float)idx;
    const float* l0 = lut + (size_t)idx * 256;
    const float2 hfi0 = *(const float2*)(l0 + 2 * L);
    const float2 hfe0 = *(const float2*)(l0 + 128 + 2 * L);
    const float2 hfi1 = *(const float2*)(l0 + 256 + 2 * L);
    const float2 hfe1 = *(const float2*)(l0 + 384 + 2 * L);
    // ev gather + squared diff (lanes mod 16 cover the 16 components)
    const int i = L & 15;
    float a = ev_f[(size_t)s * 16 + i] - ev_f[(size_t)r * 16 + i];
    float d2 = a * a;
    // segment sums (wave-uniform scalars via readlane)
    float inv0 = rlane(d2, 0);
    float inv1 = rlane(d2, 1) + rlane(d2, 2) + rlane(d2, 3);
    float inv2 = rlane(d2, 4) + rlane(d2, 5) + rlane(d2, 6) + rlane(d2, 7) + rlane(d2, 8);
    float inv3 = rlane(d2, 9) + rlane(d2, 10) + rlane(d2, 11) + rlane(d2, 12) +
                 rlane(d2, 13) + rlane(d2, 14) + rlane(d2, 15);
    // e1 for this lane's column
    float z1 = fmaf(inv0, w10, fmaf(inv1, w11, fmaf(inv2, w12, fmaf(inv3, w13, b1))));
    float e1 = silu_f(z1);
    // e2 = e1 @ we2 + be2 (e1[k] broadcast via readlane; weights in registers)
    float2 afi = b2fi, afe = b2fe;
#pragma unroll
    for (int k = 0; k < 32; k++) {
      float vfi = rlane(e1, k);
      float vfe = rlane(e1, k + 32);
      afi.x = fmaf(vfi, wfi[k].x, afi.x);
      afi.y = fmaf(vfi, wfi[k].y, afi.y);
      afe.x = fmaf(vfe, wfe[k].x, afe.x);
      afe.y = fmaf(vfe, wfe[k].y, afe.y);
    }
    float2 o2, o3;
    o2.x = fmaf(fr, hfi1.x - hfi0.x, hfi0.x) + silu_f(afi.x);
    o2.y = fmaf(fr, hfi1.y - hfi0.y, hfi0.y) + silu_f(afi.y);
    o3.x = fmaf(fr, hfe1.x - hfe0.x, hfe0.x) + silu_f(afe.x);
    o3.y = fmaf(fr, hfe1.y - hfe0.y, hfe0.y) + silu_f(afe.y);
    *(float2*)(out2 + (size_t)e * 128 + 2 * L) = o2;
    *(float2*)(out3 + (size_t)e * 128 + 2 * L) = o3;
  }
}

extern "C" void kernel_launch(void* const* d_in, const int* in_sizes, int n_in,
                              void* d_out, int out_size, void* d_ws, size_t ws_size,
                              hipStream_t stream) {
  (void)in_sizes; (void)n_in; (void)out_size; (void)ws_size;
  const float* inv_f     = (const float*)d_in[0];
  const float* ev_f      = (const float*)d_in[1];
  const int*   senders   = (const int*)d_in[2];
  const int*   receivers = (const int*)d_in[3];
  // d_in[4] sh_vectors: unused by reference
  const float* lengths   = (const float*)d_in[5];
  // d_in[6] cutoffs: unused by reference
  const float* fi_rbf_w1 = (const float*)d_in[7];
  const float* fi_rbf_b1 = (const float*)d_in[8];
  const float* fi_rbf_w2 = (const float*)d_in[9];
  const float* fi_rbf_b2 = (const float*)d_in[10];
  const float* fi_ev_w1  = (const float*)d_in[11];
  const float* fi_ev_b1  = (const float*)d_in[12];
  const float* fi_ev_w2  = (const float*)d_in[13];
  const float* fi_ev_b2  = (const float*)d_in[14];
  const float* fe_rbf_w1 = (const float*)d_in[15];
  const float* fe_rbf_b1 = (const float*)d_in[16];
  const float* fe_rbf_w2 = (const float*)d_in[17];
  const float* fe_rbf_b2 = (const float*)d_in[18];
  const float* fe_ev_w1  = (const float*)d_in[19];
  const float* fe_ev_b1  = (const float*)d_in[20];
  const float* fe_ev_w2  = (const float*)d_in[21];
  const float* fe_ev_b2  = (const float*)d_in[22];
  const float* w_int     = (const float*)d_in[23];
  const float* b_int     = (const float*)d_in[24];

  float* ws  = (float*)d_ws;
  float* lut = ws;                                  // (TT+1) * 256 floats
  float* wm  = ws + (size_t)(TT + 1) * 256;         // 132*128
  float* wb  = wm + 132 * 128;                      // 132*4

  float* out0 = (float*)d_out;                      // N x 128
  float* out1 = out0 + (size_t)N_NODES * 128;       // N x 16
  float* out2 = out1 + (size_t)N_NODES * 16;        // E x 128
  float* out3 = out2 + (size_t)N_EDGES * 128;       // E x 128

  repack_w_kernel<<<(132 * 132 + 255) / 256, 256, 0, stream>>>(w_int, wm, wb);

  LutW lw{fi_rbf_w1, fi_rbf_b1, fi_rbf_w2, fi_rbf_b2,
          fe_rbf_w1, fe_rbf_b1, fe_rbf_w2, fe_rbf_b2};
  lut_build_kernel<<<(TT + 1 + 7) / 8, 128, 0, stream>>>(lw, lut);

  node_kernel<<<256, 256, 0, stream>>>(inv_f, ev_f, wm, wb, b_int, out0, out1);

  EdgeW ew{fi_ev_w1, fi_ev_b1, fi_ev_w2, fi_ev_b2,
           fe_ev_w1, fe_ev_b1, fe_ev_w2, fe_ev_b2};
  edge_kernel<<<2048, 256, 0, stream>>>(ev_f, senders, receivers, lengths, lut, ew, out2, out3);
}